// Round 8
// baseline (186.213 us; speedup 1.0000x reference)
//
#include <hip/hip_runtime.h>
#include <hip/hip_fp16.h>
#include <float.h>

#define NC 64     // clusters
#define FD 128    // feature dim
#define LSTR 136  // LDS row stride in halfs (pad 16B; frag-read conflicts 2-way = free)

typedef _Float16 f16x8 __attribute__((ext_vector_type(8)));
typedef float f32x4 __attribute__((ext_vector_type(4)));

// ---------------- prep: fp16 cast, |x|^2, Mt build, S/done/out zero ----------------
__global__ void prep_kernel(const float* __restrict__ feat,
                            const int* __restrict__ labels,
                            float* __restrict__ sq,
                            unsigned short* __restrict__ Xh,
                            unsigned short* __restrict__ Mt,
                            float* __restrict__ S,
                            int* __restrict__ done,
                            float* __restrict__ out, int out_size, int N) {
  int t = threadIdx.x;
  int row = blockIdx.x * 32 + (t >> 3);
  int o = t & 7;
  if (row < N) {
    const float* rp = feat + (size_t)row * FD;
    float s = 0.f;
#pragma unroll
    for (int j = 0; j < 4; ++j) {
      int c4 = o + 8 * j;
      float4 v = *(const float4*)(rp + c4 * 4);
      ushort4 h;
      h.x = __half_as_ushort(__float2half(v.x));   // RNE
      h.y = __half_as_ushort(__float2half(v.y));
      h.z = __half_as_ushort(__float2half(v.z));
      h.w = __half_as_ushort(__float2half(v.w));
      *(ushort4*)&Xh[(size_t)row * FD + c4 * 4] = h;
      s = fmaf(v.x, v.x, s); s = fmaf(v.y, v.y, s);
      s = fmaf(v.z, v.z, s); s = fmaf(v.w, v.w, s);
    }
    s += __shfl_xor(s, 1); s += __shfl_xor(s, 2); s += __shfl_xor(s, 4);
    if (o == 0) sq[row] = s;
  }
  // zero S rows for this block (32 rows x NC floats = 8 floats/thread)
  if ((blockIdx.x + 1) * 32 <= N) {
    float4 z = {0.f, 0.f, 0.f, 0.f};
    size_t base = (size_t)blockIdx.x * 32 * NC + t * 8;
    *(float4*)&S[base] = z;
    *(float4*)&S[base + 4] = z;
  }
  if (blockIdx.x == 0) {
    if (t < N / 128) done[t] = 0;
    if (t < out_size) out[t] = 0.f;
  }
  // build Mt[n][col] = (labels[col]==n) ? 1.0h : 0  (8-col chunks)
  {
    int chunksPerN = N >> 3;
    int total = NC * chunksPerN;
    for (int id = blockIdx.x * 256 + t; id < total; id += gridDim.x * 256) {
      int n = id / chunksPerN;
      int c0 = (id - n * chunksPerN) * 8;
      ushort4 lo, hi;
      lo.x = (labels[c0 + 0] == n) ? 0x3C00 : 0;
      lo.y = (labels[c0 + 1] == n) ? 0x3C00 : 0;
      lo.z = (labels[c0 + 2] == n) ? 0x3C00 : 0;
      lo.w = (labels[c0 + 3] == n) ? 0x3C00 : 0;
      hi.x = (labels[c0 + 4] == n) ? 0x3C00 : 0;
      hi.y = (labels[c0 + 5] == n) ? 0x3C00 : 0;
      hi.z = (labels[c0 + 6] == n) ? 0x3C00 : 0;
      hi.w = (labels[c0 + 7] == n) ? 0x3C00 : 0;
      *(ushort4*)&Mt[(size_t)n * N + c0] = lo;
      *(ushort4*)&Mt[(size_t)n * N + c0 + 4] = hi;
    }
  }
}

// ---------------- main: fp16 MFMA Gram + MFMA segment-sum + fused scoring ----------
// Structure as round 7 (operand-swapped dist MFMA, D round-trip through Bh, one-hot
// M from global Mt). New: (a) register prefetch of the next B col-tile issued before
// the head barrier's consumers, (b) last-finisher block per 128-row group scores its
// rows in-kernel (device-scope done[] counter), removing the score dispatch.
__global__ __launch_bounds__(256, 2)
void mfma_tile_kernel(const unsigned short* __restrict__ Xh,
                      const float* __restrict__ sq,
                      const unsigned short* __restrict__ Mt,
                      const int* __restrict__ labels,
                      float* __restrict__ S,
                      int* __restrict__ done,
                      float* __restrict__ out,
                      int N, int colsPerSplit) {
  __shared__ __align__(16) unsigned short Ah[128 * LSTR];  // 34816 B
  __shared__ __align__(16) unsigned short Bh[128 * LSTR];  // 34816 B, reused as D
  __shared__ int lastFlag;

  const int t = threadIdx.x;
  const int R = blockIdx.x * 128;
  const int cBeg = blockIdx.y * colsPerSplit;
  const int wave = t >> 6, lane = t & 63;
  const int mm = lane & 15, quad = lane >> 4;
  const int wr = wave >> 1, wc = wave & 1;   // 2x2 wave grid

  // stage A full-K: 2048 x 16B chunks over 256 threads
  const int sr = t >> 4, sk0 = (t & 15) * 8;       // this thread's 8 staging slots
#pragma unroll
  for (int it = 0; it < 8; ++it)
    *(uint4*)&Ah[(sr + it * 16) * LSTR + sk0] =
        *(const uint4*)&Xh[(size_t)(R + sr + it * 16) * FD + sk0];

  // initial B prefetch (col-tile 0) into registers
  uint4 bpref[8];
#pragma unroll
  for (int it = 0; it < 8; ++it)
    bpref[it] = *(const uint4*)&Xh[(size_t)(cBeg + sr + it * 16) * FD + sk0];

  float sqi_r[4];
#pragma unroll
  for (int ib = 0; ib < 4; ++ib)
    sqi_r[ib] = sq[R + wr * 64 + ib * 16 + mm];

  f32x4 sacc[2][4];
#pragma unroll
  for (int rt = 0; rt < 2; ++rt)
#pragma unroll
    for (int lt = 0; lt < 4; ++lt) sacc[rt][lt] = (f32x4)0.f;

  const int numTiles = colsPerSplit / 128;
  for (int ct = 0; ct < numTiles; ++ct) {
    const int C0 = cBeg + ct * 128;
    __syncthreads();                         // prev S-pass done before Bh overwrite
#pragma unroll
    for (int it = 0; it < 8; ++it)
      *(uint4*)&Bh[(sr + it * 16) * LSTR + sk0] = bpref[it];
    // prefetch next col-tile (plain loads stay in flight across s_barrier)
    const int nC0 = (ct + 1 < numTiles) ? C0 + 128 : cBeg;
#pragma unroll
    for (int it = 0; it < 8; ++it)
      bpref[it] = *(const uint4*)&Xh[(size_t)(nC0 + sr + it * 16) * FD + sk0];
    float sjr[4][4];
#pragma unroll
    for (int jb = 0; jb < 4; ++jb)
#pragma unroll
      for (int r = 0; r < 4; ++r)
        sjr[jb][r] = sq[C0 + wc * 64 + jb * 16 + quad * 4 + r];
    __syncthreads();                         // Bh ready

    // Dist pass: operands swapped -> transposed C/D fragments
    f32x4 dacc[4][4];
#pragma unroll
    for (int ib = 0; ib < 4; ++ib)
#pragma unroll
      for (int jb = 0; jb < 4; ++jb) dacc[ib][jb] = (f32x4)0.f;

#pragma unroll
    for (int ks = 0; ks < 4; ++ks) {
      const int ko = ks * 32 + quad * 8;
      f16x8 af[4], bf[4];
#pragma unroll
      for (int ib = 0; ib < 4; ++ib)
        af[ib] = *(const f16x8*)&Ah[(wr * 64 + ib * 16 + mm) * LSTR + ko];
#pragma unroll
      for (int jb = 0; jb < 4; ++jb)
        bf[jb] = *(const f16x8*)&Bh[(wc * 64 + jb * 16 + mm) * LSTR + ko];
#pragma unroll
      for (int ib = 0; ib < 4; ++ib)
#pragma unroll
        for (int jb = 0; jb < 4; ++jb)
          dacc[ib][jb] = __builtin_amdgcn_mfma_f32_16x16x32_f16(bf[jb], af[ib], dacc[ib][jb], 0, 0, 0);
    }
    __syncthreads();                         // all waves done reading Bh -> reuse as D

    // epilogue: lane holds row (lane&15), 4 contiguous cols (quad*4+r)
    const bool hasDiag = (R == C0);
#pragma unroll
    for (int ib = 0; ib < 4; ++ib) {
      const int rowLocal = wr * 64 + ib * 16 + mm;
      const float si = sqi_r[ib];
#pragma unroll
      for (int jb = 0; jb < 4; ++jb) {
        const int colBase = wc * 64 + jb * 16 + quad * 4;
        float d[4];
#pragma unroll
        for (int r = 0; r < 4; ++r) {
          float d2 = fmaf(-2.f, dacc[ib][jb][r], si + sjr[jb][r]);
          d[r] = __builtin_amdgcn_sqrtf(fmaxf(d2, 0.f));  // sqrt(0)=0: grad-safe
        }
        if (hasDiag) {
#pragma unroll
          for (int r = 0; r < 4; ++r)
            if (rowLocal == colBase + r) d[r] = 0.f;
        }
        uint2 pk;
        pk.x = __builtin_bit_cast(unsigned, __builtin_amdgcn_cvt_pkrtz(d[0], d[1]));
        pk.y = __builtin_bit_cast(unsigned, __builtin_amdgcn_cvt_pkrtz(d[2], d[3]));
        *(uint2*)&Bh[rowLocal * LSTR + colBase] = pk;    // 8B store, aligned
      }
    }
    __syncthreads();                         // D ready

    // S-pass: S_tile[128xNC] += D[128x128] x M[128xNC]; M frags from global Mt
#pragma unroll
    for (int ks = 0; ks < 4; ++ks) {
      const int ko = ks * 32 + quad * 8;
      f16x8 da0 = *(const f16x8*)&Bh[(wave * 32 + mm) * LSTR + ko];
      f16x8 da1 = *(const f16x8*)&Bh[(wave * 32 + 16 + mm) * LSTR + ko];
#pragma unroll
      for (int lt = 0; lt < 4; ++lt) {
        f16x8 mb = *(const f16x8*)&Mt[(size_t)(lt * 16 + mm) * N + C0 + ks * 32 + quad * 8];
        sacc[0][lt] = __builtin_amdgcn_mfma_f32_16x16x32_f16(da0, mb, sacc[0][lt], 0, 0, 0);
        sacc[1][lt] = __builtin_amdgcn_mfma_f32_16x16x32_f16(da1, mb, sacc[1][lt], 0, 0, 0);
      }
    }
  }

  // flush: one atomic per S entry (colSplit blocks contend per row)
#pragma unroll
  for (int rt = 0; rt < 2; ++rt)
#pragma unroll
    for (int lt = 0; lt < 4; ++lt)
#pragma unroll
      for (int r = 0; r < 4; ++r) {
        int row = wave * 32 + rt * 16 + quad * 4 + r;
        atomicAdd(&S[(size_t)(R + row) * NC + lt * 16 + mm], sacc[rt][lt][r]);
      }

  // -------- fused scoring: last finisher for this 128-row group --------
  __threadfence();                           // drain + release this thread's atomics
  __syncthreads();                           // all threads' atomics complete
  if (t == 0) {
    int old = atomicAdd(&done[blockIdx.x], 1);
    lastFlag = (old == (int)gridDim.y - 1) ? 1 : 0;
  }
  __syncthreads();
  if (!lastFlag) return;
  __threadfence();                           // acquire side

  int* hist = (int*)Ah;                      // alias dead LDS
  float* red = (float*)Bh;
  if (t < NC) hist[t] = 0;
  __syncthreads();
  const int4* lab4 = (const int4*)labels;
  for (int i = t; i < N / 4; i += 256) {
    int4 v = lab4[i];
    atomicAdd(&hist[v.x], 1); atomicAdd(&hist[v.y], 1);
    atomicAdd(&hist[v.z], 1); atomicAdd(&hist[v.w], 1);
  }
  __syncthreads();

  float score = 0.f;
  if (t < 128) {
    int i = R + t;
    int li = labels[i];
    float own = (float)hist[li];
    float a = 0.f, b = FLT_MAX;
    const float* Si = S + (size_t)i * NC;
#pragma unroll
    for (int c = 0; c < NC; ++c) {
      // agent-scope load: bypass L1, see other XCDs' atomics
      float s = __hip_atomic_load(&Si[c], __ATOMIC_RELAXED, __HIP_MEMORY_SCOPE_AGENT);
      float cf = (float)hist[c];
      if (c == li) a = s / fmaxf(own - 1.f, 1.f);
      else if (cf != 0.f) b = fminf(b, s / cf);
    }
    float mx = fmaxf(a, b);
    score = (own > 1.f) ? (b - a) / mx : 0.f;
  }
  red[t] = score;
  __syncthreads();
  for (int sft = 128; sft > 0; sft >>= 1) {
    if (t < sft) red[t] += red[t + sft];
    __syncthreads();
  }
  if (t == 0) atomicAdd(out, red[0] / (float)N);
}

extern "C" void kernel_launch(void* const* d_in, const int* in_sizes, int n_in,
                              void* d_out, int out_size, void* d_ws, size_t ws_size,
                              hipStream_t stream) {
  const float* feat = (const float*)d_in[0];
  const int* labels = (const int*)d_in[1];
  const int N = in_sizes[1];            // 8192; D=128, C=64 fixed by the reference
  float* out = (float*)d_out;
  char* ws = (char*)d_ws;

  // ws: done(256B) | sq(N*4) | Xh(N*128*2) | Mt(64*N*2) | S(N*64*4)  ~5.03 MB @8192
  int*   done = (int*)ws;
  float* sq   = (float*)(ws + 256);
  size_t o = 256 + (size_t)N * 4;
  o = (o + 255) & ~(size_t)255;
  unsigned short* Xh = (unsigned short*)(ws + o);                       // N*FD*2
  unsigned short* Mt = (unsigned short*)(ws + o + (size_t)N * FD * 2);  // NC*N*2
  float* S = (float*)(ws + o + (size_t)N * FD * 2 + (size_t)NC * N * 2);

  prep_kernel<<<(N + 31) / 32, 256, 0, stream>>>(feat, labels, sq, Xh, Mt, S,
                                                 done, out, out_size, N);

  const int colSplit = 8;               // 64 x 8 = 512 blocks = 2/CU (4 waves each)
  dim3 grid(N / 128, colSplit);
  mfma_tile_kernel<<<grid, 256, 0, stream>>>(Xh, sq, Mt, labels, S, done, out,
                                             N, N / colSplit);
}

// Round 9
// 167.519 us; speedup vs baseline: 1.1116x; 1.1116x over previous
//
#include <hip/hip_runtime.h>
#include <hip/hip_fp16.h>
#include <float.h>

#define NC 64     // clusters
#define FD 128    // feature dim
#define LSTR 136  // LDS row stride in halfs (pad 16B; frag-read conflicts 2-way = free)

typedef _Float16 f16x8 __attribute__((ext_vector_type(8)));
typedef float f32x4 __attribute__((ext_vector_type(4)));

// ---------------- prep: fp16 cast, |x|^2, Mt build, S/done/out zero ----------------
__global__ void prep_kernel(const float* __restrict__ feat,
                            const int* __restrict__ labels,
                            float* __restrict__ sq,
                            unsigned short* __restrict__ Xh,
                            unsigned short* __restrict__ Mt,
                            float* __restrict__ S,
                            int* __restrict__ done,
                            float* __restrict__ out, int out_size, int N) {
  int t = threadIdx.x;
  int row = blockIdx.x * 32 + (t >> 3);
  int o = t & 7;
  if (row < N) {
    const float* rp = feat + (size_t)row * FD;
    float s = 0.f;
#pragma unroll
    for (int j = 0; j < 4; ++j) {
      int c4 = o + 8 * j;
      float4 v = *(const float4*)(rp + c4 * 4);
      ushort4 h;
      h.x = __half_as_ushort(__float2half(v.x));   // RNE
      h.y = __half_as_ushort(__float2half(v.y));
      h.z = __half_as_ushort(__float2half(v.z));
      h.w = __half_as_ushort(__float2half(v.w));
      *(ushort4*)&Xh[(size_t)row * FD + c4 * 4] = h;
      s = fmaf(v.x, v.x, s); s = fmaf(v.y, v.y, s);
      s = fmaf(v.z, v.z, s); s = fmaf(v.w, v.w, s);
    }
    s += __shfl_xor(s, 1); s += __shfl_xor(s, 2); s += __shfl_xor(s, 4);
    if (o == 0) sq[row] = s;
  }
  // zero S rows for this block (32 rows x NC floats = 8 floats/thread)
  if ((blockIdx.x + 1) * 32 <= N) {
    float4 z = {0.f, 0.f, 0.f, 0.f};
    size_t base = (size_t)blockIdx.x * 32 * NC + t * 8;
    *(float4*)&S[base] = z;
    *(float4*)&S[base + 4] = z;
  }
  if (blockIdx.x == 0) {
    if (t < N / 128) done[t] = 0;
    if (t < out_size) out[t] = 0.f;
  }
  // build Mt[n][col] = (labels[col]==n) ? 1.0h : 0  (8-col chunks)
  {
    int chunksPerN = N >> 3;
    int total = NC * chunksPerN;
    for (int id = blockIdx.x * 256 + t; id < total; id += gridDim.x * 256) {
      int n = id / chunksPerN;
      int c0 = (id - n * chunksPerN) * 8;
      ushort4 lo, hi;
      lo.x = (labels[c0 + 0] == n) ? 0x3C00 : 0;
      lo.y = (labels[c0 + 1] == n) ? 0x3C00 : 0;
      lo.z = (labels[c0 + 2] == n) ? 0x3C00 : 0;
      lo.w = (labels[c0 + 3] == n) ? 0x3C00 : 0;
      hi.x = (labels[c0 + 4] == n) ? 0x3C00 : 0;
      hi.y = (labels[c0 + 5] == n) ? 0x3C00 : 0;
      hi.z = (labels[c0 + 6] == n) ? 0x3C00 : 0;
      hi.w = (labels[c0 + 7] == n) ? 0x3C00 : 0;
      *(ushort4*)&Mt[(size_t)n * N + c0] = lo;
      *(ushort4*)&Mt[(size_t)n * N + c0 + 4] = hi;
    }
  }
}

// ---------------- main: fp16 MFMA Gram + MFMA segment-sum + fused scoring ----------
// Round-7 structure (operand-swapped dist MFMA, D round-trip through Bh, one-hot M
// from global Mt). Fused last-finisher scoring WITHOUT __threadfence: S atomics are
// device-coherent already; ordering via raw `s_waitcnt vmcnt(0)` (no L2 writeback).
// Mt frags prefetched post-epilogue so they complete inside the D-ready barrier's
// mandatory vmcnt drain instead of stalling the S-pass.
__global__ __launch_bounds__(256, 2)
void mfma_tile_kernel(const unsigned short* __restrict__ Xh,
                      const float* __restrict__ sq,
                      const unsigned short* __restrict__ Mt,
                      const int* __restrict__ labels,
                      float* __restrict__ S,
                      int* __restrict__ done,
                      float* __restrict__ out,
                      int N, int colsPerSplit) {
  __shared__ __align__(16) unsigned short Ah[128 * LSTR];  // 34816 B
  __shared__ __align__(16) unsigned short Bh[128 * LSTR];  // 34816 B, reused as D
  __shared__ int lastFlag;

  const int t = threadIdx.x;
  const int R = blockIdx.x * 128;
  const int cBeg = blockIdx.y * colsPerSplit;
  const int wave = t >> 6, lane = t & 63;
  const int mm = lane & 15, quad = lane >> 4;
  const int wr = wave >> 1, wc = wave & 1;   // 2x2 wave grid

  // stage A full-K: 2048 x 16B chunks over 256 threads
  const int sr = t >> 4, sk0 = (t & 15) * 8;
#pragma unroll
  for (int it = 0; it < 8; ++it)
    *(uint4*)&Ah[(sr + it * 16) * LSTR + sk0] =
        *(const uint4*)&Xh[(size_t)(R + sr + it * 16) * FD + sk0];

  // initial B prefetch (col-tile 0) into registers
  uint4 bpref[8];
#pragma unroll
  for (int it = 0; it < 8; ++it)
    bpref[it] = *(const uint4*)&Xh[(size_t)(cBeg + sr + it * 16) * FD + sk0];

  float sqi_r[4];
#pragma unroll
  for (int ib = 0; ib < 4; ++ib)
    sqi_r[ib] = sq[R + wr * 64 + ib * 16 + mm];

  f32x4 sacc[2][4];
#pragma unroll
  for (int rt = 0; rt < 2; ++rt)
#pragma unroll
    for (int lt = 0; lt < 4; ++lt) sacc[rt][lt] = (f32x4)0.f;

  const int numTiles = colsPerSplit / 128;
  for (int ct = 0; ct < numTiles; ++ct) {
    const int C0 = cBeg + ct * 128;
    __syncthreads();                         // prev S-pass done before Bh overwrite
#pragma unroll
    for (int it = 0; it < 8; ++it)
      *(uint4*)&Bh[(sr + it * 16) * LSTR + sk0] = bpref[it];
    // prefetch next col-tile
    const int nC0 = (ct + 1 < numTiles) ? C0 + 128 : cBeg;
#pragma unroll
    for (int it = 0; it < 8; ++it)
      bpref[it] = *(const uint4*)&Xh[(size_t)(nC0 + sr + it * 16) * FD + sk0];
    float sjr[4][4];
#pragma unroll
    for (int jb = 0; jb < 4; ++jb)
#pragma unroll
      for (int r = 0; r < 4; ++r)
        sjr[jb][r] = sq[C0 + wc * 64 + jb * 16 + quad * 4 + r];
    __syncthreads();                         // Bh ready

    // Dist pass: operands swapped -> transposed C/D fragments
    f32x4 dacc[4][4];
#pragma unroll
    for (int ib = 0; ib < 4; ++ib)
#pragma unroll
      for (int jb = 0; jb < 4; ++jb) dacc[ib][jb] = (f32x4)0.f;

#pragma unroll
    for (int ks = 0; ks < 4; ++ks) {
      const int ko = ks * 32 + quad * 8;
      f16x8 af[4], bf[4];
#pragma unroll
      for (int ib = 0; ib < 4; ++ib)
        af[ib] = *(const f16x8*)&Ah[(wr * 64 + ib * 16 + mm) * LSTR + ko];
#pragma unroll
      for (int jb = 0; jb < 4; ++jb)
        bf[jb] = *(const f16x8*)&Bh[(wc * 64 + jb * 16 + mm) * LSTR + ko];
#pragma unroll
      for (int ib = 0; ib < 4; ++ib)
#pragma unroll
        for (int jb = 0; jb < 4; ++jb)
          dacc[ib][jb] = __builtin_amdgcn_mfma_f32_16x16x32_f16(bf[jb], af[ib], dacc[ib][jb], 0, 0, 0);
    }
    __syncthreads();                         // all waves done reading Bh -> reuse as D

    // epilogue: lane holds row (lane&15), 4 contiguous cols (quad*4+r)
    const bool hasDiag = (R == C0);
#pragma unroll
    for (int ib = 0; ib < 4; ++ib) {
      const int rowLocal = wr * 64 + ib * 16 + mm;
      const float si = sqi_r[ib];
#pragma unroll
      for (int jb = 0; jb < 4; ++jb) {
        const int colBase = wc * 64 + jb * 16 + quad * 4;
        float d[4];
#pragma unroll
        for (int r = 0; r < 4; ++r) {
          float d2 = fmaf(-2.f, dacc[ib][jb][r], si + sjr[jb][r]);
          d[r] = __builtin_amdgcn_sqrtf(fmaxf(d2, 0.f));  // sqrt(0)=0: grad-safe
        }
        if (hasDiag) {
#pragma unroll
          for (int r = 0; r < 4; ++r)
            if (rowLocal == colBase + r) d[r] = 0.f;
        }
        uint2 pk;
        pk.x = __builtin_bit_cast(unsigned, __builtin_amdgcn_cvt_pkrtz(d[0], d[1]));
        pk.y = __builtin_bit_cast(unsigned, __builtin_amdgcn_cvt_pkrtz(d[2], d[3]));
        *(uint2*)&Bh[rowLocal * LSTR + colBase] = pk;    // 8B store, aligned
      }
    }

    // prefetch the 16 Mt frags; they complete inside the barrier's vmcnt drain
    f16x8 mbp[4][4];
#pragma unroll
    for (int ks = 0; ks < 4; ++ks)
#pragma unroll
      for (int lt = 0; lt < 4; ++lt)
        mbp[ks][lt] = *(const f16x8*)&Mt[(size_t)(lt * 16 + mm) * N + C0 + ks * 32 + quad * 8];
    __syncthreads();                         // D ready (drains mbp loads too)

    // S-pass: S_tile[128xNC] += D[128x128] x M[128xNC]
#pragma unroll
    for (int ks = 0; ks < 4; ++ks) {
      const int ko = ks * 32 + quad * 8;
      f16x8 da0 = *(const f16x8*)&Bh[(wave * 32 + mm) * LSTR + ko];
      f16x8 da1 = *(const f16x8*)&Bh[(wave * 32 + 16 + mm) * LSTR + ko];
#pragma unroll
      for (int lt = 0; lt < 4; ++lt) {
        sacc[0][lt] = __builtin_amdgcn_mfma_f32_16x16x32_f16(da0, mbp[ks][lt], sacc[0][lt], 0, 0, 0);
        sacc[1][lt] = __builtin_amdgcn_mfma_f32_16x16x32_f16(da1, mbp[ks][lt], sacc[1][lt], 0, 0, 0);
      }
    }
  }

  // flush: one atomic per S entry (colSplit blocks contend per row)
#pragma unroll
  for (int rt = 0; rt < 2; ++rt)
#pragma unroll
    for (int lt = 0; lt < 4; ++lt)
#pragma unroll
      for (int r = 0; r < 4; ++r) {
        int row = wave * 32 + rt * 16 + quad * 4 + r;
        atomicAdd(&S[(size_t)(R + row) * NC + lt * 16 + mm], sacc[rt][lt][r]);
      }

  // -------- fused scoring: last finisher for this 128-row group --------
  // S atomics are device-coherent (coherence-point ops); we only need ordering:
  // wait for THIS wave's atomics to complete before signaling done. No cache
  // maintenance (no __threadfence -> no L2 writeback storm).
  asm volatile("s_waitcnt vmcnt(0)" ::: "memory");
  __syncthreads();                           // all 4 waves' atomics complete
  if (t == 0) {
    int old = atomicAdd(&done[blockIdx.x], 1);
    lastFlag = (old == (int)gridDim.y - 1) ? 1 : 0;
  }
  __syncthreads();
  if (!lastFlag) return;

  int* hist = (int*)Ah;                      // alias dead LDS
  float* red = (float*)Bh;
  if (t < NC) hist[t] = 0;
  __syncthreads();
  const int4* lab4 = (const int4*)labels;
  for (int i = t; i < N / 4; i += 256) {
    int4 v = lab4[i];
    atomicAdd(&hist[v.x], 1); atomicAdd(&hist[v.y], 1);
    atomicAdd(&hist[v.z], 1); atomicAdd(&hist[v.w], 1);
  }
  __syncthreads();

  float score = 0.f;
  if (t < 128) {
    int i = R + t;
    int li = labels[i];
    float own = (float)hist[li];
    float a = 0.f, b = FLT_MAX;
    const float* Si = S + (size_t)i * NC;
#pragma unroll
    for (int c = 0; c < NC; ++c) {
      // agent-scope relaxed load: bypass L1/local-L2, read the coherence point
      float s = __hip_atomic_load(&Si[c], __ATOMIC_RELAXED, __HIP_MEMORY_SCOPE_AGENT);
      float cf = (float)hist[c];
      if (c == li) a = s / fmaxf(own - 1.f, 1.f);
      else if (cf != 0.f) b = fminf(b, s / cf);
    }
    float mx = fmaxf(a, b);
    score = (own > 1.f) ? (b - a) / mx : 0.f;
  }
  red[t] = score;
  __syncthreads();
  for (int sft = 128; sft > 0; sft >>= 1) {
    if (t < sft) red[t] += red[t + sft];
    __syncthreads();
  }
  if (t == 0) atomicAdd(out, red[0] / (float)N);
}

extern "C" void kernel_launch(void* const* d_in, const int* in_sizes, int n_in,
                              void* d_out, int out_size, void* d_ws, size_t ws_size,
                              hipStream_t stream) {
  const float* feat = (const float*)d_in[0];
  const int* labels = (const int*)d_in[1];
  const int N = in_sizes[1];            // 8192; D=128, C=64 fixed by the reference
  float* out = (float*)d_out;
  char* ws = (char*)d_ws;

  // ws: done(256B) | sq(N*4) | Xh(N*128*2) | Mt(64*N*2) | S(N*64*4)  ~5.03 MB @8192
  int*   done = (int*)ws;
  float* sq   = (float*)(ws + 256);
  size_t o = 256 + (size_t)N * 4;
  o = (o + 255) & ~(size_t)255;
  unsigned short* Xh = (unsigned short*)(ws + o);                       // N*FD*2
  unsigned short* Mt = (unsigned short*)(ws + o + (size_t)N * FD * 2);  // NC*N*2
  float* S = (float*)(ws + o + (size_t)N * FD * 2 + (size_t)NC * N * 2);

  prep_kernel<<<(N + 31) / 32, 256, 0, stream>>>(feat, labels, sq, Xh, Mt, S,
                                                 done, out, out_size, N);

  const int colSplit = 8;               // 64 x 8 = 512 blocks = 2/CU (4 waves each)
  dim3 grid(N / 128, colSplit);
  mfma_tile_kernel<<<grid, 256, 0, stream>>>(Xh, sq, Mt, labels, S, done, out,
                                             N, N / colSplit);
}